// Round 1
// baseline (1279.652 us; speedup 1.0000x reference)
//
#include <hip/hip_runtime.h>

// out_i = 0.1 * x_i * sum_j A[i][j] * (1 - x_j)
// n = 16384, A row-major fp32 (1.07 GB, read once -> nontemporal), x fp32 [n,1].
// Memory-bound. One wave (64 lanes) per row, 4 waves/block, 4096 blocks.

#define N 16384

typedef float f32x4 __attribute__((ext_vector_type(4)));

__device__ __forceinline__ float term(f32x4 a, f32x4 xx) {
  return a.x * (1.f - xx.x) + a.y * (1.f - xx.y)
       + a.z * (1.f - xx.z) + a.w * (1.f - xx.w);
}

__global__ __launch_bounds__(256) void epidemic_matvec(
    const float* __restrict__ x,
    const float* __restrict__ A,
    float* __restrict__ out) {
  const int wave = threadIdx.x >> 6;   // 0..3
  const int lane = threadIdx.x & 63;
  const int row  = blockIdx.x * 4 + wave;

  const f32x4* __restrict__ Arow =
      reinterpret_cast<const f32x4*>(A + (size_t)row * N);
  const f32x4* __restrict__ xv = reinterpret_cast<const f32x4*>(x);

  // 16384 / 4 = 4096 f32x4 per row; 64 lanes * 8 f32x4 per outer iter -> 8 iters.
  // All 16 loads of an iteration issue before any consumption: up to 16
  // outstanding VMEM ops/wave to cover ~900-cycle HBM latency.
  float acc0 = 0.f, acc1 = 0.f, acc2 = 0.f, acc3 = 0.f;

  for (int it = 0; it < 8; ++it) {
    const int base = it * 512 + lane;

    // A: streaming, read-once -> nontemporal (nt) so it does not evict x
    // from L2/L3.
    f32x4 a0 = __builtin_nontemporal_load(Arow + base + 0 * 64);
    f32x4 a1 = __builtin_nontemporal_load(Arow + base + 1 * 64);
    f32x4 a2 = __builtin_nontemporal_load(Arow + base + 2 * 64);
    f32x4 a3 = __builtin_nontemporal_load(Arow + base + 3 * 64);
    f32x4 a4 = __builtin_nontemporal_load(Arow + base + 4 * 64);
    f32x4 a5 = __builtin_nontemporal_load(Arow + base + 5 * 64);
    f32x4 a6 = __builtin_nontemporal_load(Arow + base + 6 * 64);
    f32x4 a7 = __builtin_nontemporal_load(Arow + base + 7 * 64);

    // x: heavily reused across rows -> normal cached loads (L2/L3 resident).
    f32x4 x0 = xv[base + 0 * 64];
    f32x4 x1 = xv[base + 1 * 64];
    f32x4 x2 = xv[base + 2 * 64];
    f32x4 x3 = xv[base + 3 * 64];
    f32x4 x4 = xv[base + 4 * 64];
    f32x4 x5 = xv[base + 5 * 64];
    f32x4 x6 = xv[base + 6 * 64];
    f32x4 x7 = xv[base + 7 * 64];

    // 4 independent accumulator chains.
    acc0 += term(a0, x0);
    acc1 += term(a1, x1);
    acc2 += term(a2, x2);
    acc3 += term(a3, x3);
    acc0 += term(a4, x4);
    acc1 += term(a5, x5);
    acc2 += term(a6, x6);
    acc3 += term(a7, x7);
  }

  float acc = (acc0 + acc1) + (acc2 + acc3);

  // 64-wide wave reduction (wave = 64 on CDNA, not 32)
#pragma unroll
  for (int off = 32; off > 0; off >>= 1)
    acc += __shfl_down(acc, off, 64);

  if (lane == 0)
    out[row] = 0.1f * x[row] * acc;
}

extern "C" void kernel_launch(void* const* d_in, const int* in_sizes, int n_in,
                              void* d_out, int out_size, void* d_ws, size_t ws_size,
                              hipStream_t stream) {
  // setup_inputs order: t (1), x (16384), A (16384*16384) -- all fp32
  const float* x = (const float*)d_in[1];
  const float* A = (const float*)d_in[2];
  float* out = (float*)d_out;

  // 16384 rows / 4 rows-per-block = 4096 blocks
  epidemic_matvec<<<N / 4, 256, 0, stream>>>(x, A, out);
}